// Round 16
// baseline (193.749 us; speedup 1.0000x reference)
//
#include <hip/hip_runtime.h>
#include <hip/hip_bf16.h>
#include <cstdint>
#include <cstddef>

// Problem constants
#define BS_TOT  12288   // 3 * 4096 rows
#define DIM     256     // embedding dim
#define BATCH_  4096
#define NTILE   96      // BS_TOT / 128
#define NPAIR   4656    // NTILE*(NTILE+1)/2 — triangular tile pairs (incl diag)
#define NBLOCKS 512     // persistent, 2 blocks/CU; ~9 pairs each

typedef float f32x16 __attribute__((ext_vector_type(16)));
typedef int   i32x8  __attribute__((ext_vector_type(8)));

// ---------------------------------------------------------------------------
// Kernel 1: row-normalize -> fp8 e4m3 rows scaled by sqrt(10*log2(e)):
// acc = 10*log2(e)*cos, so epilogue exp(10 cos) = exp2(acc) = bare v_exp_f32.
// Also fp32 inv-norms (exact numerator path) + zero den + zero out.
// ---------------------------------------------------------------------------
__global__ __launch_bounds__(256) void normalize_kernel(const float* __restrict__ x,
                                                        uint8_t* __restrict__ xn,
                                                        float* __restrict__ invn,
                                                        float* __restrict__ den,
                                                        float* __restrict__ out,
                                                        int osz) {
  if (blockIdx.x == 0 && (int)threadIdx.x < osz) out[threadIdx.x] = 0.0f;
  const int wave = threadIdx.x >> 6;
  const int lane = threadIdx.x & 63;
  const int row  = blockIdx.x * 4 + wave;
  const float4 v = ((const float4*)(x + (size_t)row * DIM))[lane];
  float ss = v.x*v.x + v.y*v.y + v.z*v.z + v.w*v.w;
  #pragma unroll
  for (int off = 1; off < 64; off <<= 1) ss += __shfl_xor(ss, off, 64);
  const float s = 1.0f / fmaxf(sqrtf(ss), 1e-6f);
  if (lane == 0) { invn[row] = s; den[row] = 0.0f; }
  const float sc = s * 3.79828286f;   // sqrt(10 * log2(e))
  unsigned int w = __builtin_amdgcn_cvt_pk_fp8_f32(v.x * sc, v.y * sc, 0u, false);
  w = __builtin_amdgcn_cvt_pk_fp8_f32(v.z * sc, v.w * sc, w, true);
  ((unsigned int*)(xn + (size_t)row * DIM))[lane] = w;
}

// ---------------------------------------------------------------------------
// triangular decode: t -> (tI <= tJ)
// ---------------------------------------------------------------------------
__device__ __forceinline__ void decode_pair(int t, int& tI, int& tJ) {
  int j = (int)((sqrtf(8.0f * (float)t + 1.0f) - 1.0f) * 0.5f);
  while ((j + 1) * (j + 2) / 2 <= t) j++;
  while (j * (j + 1) / 2 > t) j--;
  tI = t - j * (j + 1) / 2;
  tJ = j;
}

// Raw workgroup barrier WITHOUT the vmcnt(0) drain __syncthreads would emit:
// waits only LDS ops, so the cross-pair prefetch global loads stay in flight
// (R14-proven correct: absmax 0.0 with this discipline).
#define BARRIER_NO_VMDRAIN() asm volatile("s_waitcnt lgkmcnt(0)\n\ts_barrier" ::: "memory")

// ---------------------------------------------------------------------------
// Kernel 2: PERSISTENT symmetric triangular GEMM, MX-scaled fp8 32x32x64,
// R12 shape (256 thr, 4 waves in 2x2, 2 blocks/CU), cross-pair REGISTER
// prefetch pipeline, TWO-PASS K-loop:
//   pass 1: acc  = A·B^T  -> epilogue -> den[tJ cols]   (64 AGPR)
//   pass 2: accT = B·A^T  (re-reads the same LDS frags, reuses the freed
//           64 AGPR)      -> epilogue -> den[tI cols]
// Halving live accumulators is what lets the 64 prefetch VGPRs fit in the
// unified 256-reg/wave file at 2 waves/SIMD — the fix for R14's scratch
// spill (WRITE_SIZE 300 MB, arch 128 + acc 128 AGPR left no room).
// Diagonal pairs: pass 1 only.
//
// LDS: 32-B-unit XOR swizzle  addr = row*256 + ((k32 ^ (row&7))*32) + sub16
// Fragment ks: lane (l31,half) reads 32 B at unit (2ks+half)^(l31&7),
// one aligned i32x8 (2 x ds_read_b128).
// C/D layout (HW-verified): col = lane&31, row = (reg&3)+8*(reg>>2)+4*half.
// Mask: exclude iff col%4 == row%4  ->  ((l31 ^ r) & 3) == 0.
// ---------------------------------------------------------------------------
__global__ __launch_bounds__(256, 2) void gemm_den_kernel(const uint8_t* __restrict__ xn,
                                                          float* __restrict__ den) {
  __shared__ __align__(16) uint8_t As[128 * 256];   // 32 KB
  __shared__ __align__(16) uint8_t Bs[128 * 256];   // 32 KB

  const int tid  = threadIdx.x;
  const int wave = tid >> 6, lane = tid & 63;
  const int wr   = wave >> 1, wc = wave & 1;
  const int l31  = lane & 31, half = lane >> 5;
  const int e7   = l31 & 7;
  const int rowA0 = (wr * 64 + l31) * 256;
  const int rowB0 = (wc * 64 + l31) * 256;

  // per-thread staging maps (constant across pairs)
  size_t goff[8]; int wadr[8];
  #pragma unroll
  for (int c = 0; c < 8; c++) {
    const int q   = c * 256 + tid;
    const int row = q >> 4, k16 = q & 15;
    goff[c] = (size_t)row * DIM + (size_t)k16 * 16;
    wadr[c] = row * 256 + (((k16 >> 1) ^ (row & 7)) * 32) + (k16 & 1) * 16;
  }

  int tcur = blockIdx.x;
  int nI, nJ;
  decode_pair(tcur, nI, nJ);

  int4 chA[8], chB[8];
  {
    const uint8_t* Ab = xn + (size_t)nI * 128 * DIM;
    const uint8_t* Bb = xn + (size_t)nJ * 128 * DIM;
    #pragma unroll
    for (int c = 0; c < 8; c++) {
      chA[c] = *(const int4*)(Ab + goff[c]);
      chB[c] = *(const int4*)(Bb + goff[c]);
    }
  }
  int curI = nI, curJ = nJ;

  for (;;) {
    // ---- stage current pair (consumes prefetch regs; vmcnt drains by dep)
    #pragma unroll
    for (int c = 0; c < 8; c++) {
      *(int4*)(As + wadr[c]) = chA[c];
      *(int4*)(Bs + wadr[c]) = chB[c];
    }
    __syncthreads();                       // writes visible; vmcnt already 0

    // ---- prefetch NEXT pair into registers (in flight across both passes)
    const int  tnext = tcur + NBLOCKS;
    const bool more  = (tnext < NPAIR);
    if (more) {
      decode_pair(tnext, nI, nJ);
      const uint8_t* An = xn + (size_t)nI * 128 * DIM;
      const uint8_t* Bn = xn + (size_t)nJ * 128 * DIM;
      #pragma unroll
      for (int c = 0; c < 8; c++) {
        chA[c] = *(const int4*)(An + goff[c]);
        chB[c] = *(const int4*)(Bn + goff[c]);
      }
    }

    const bool offd = (curI != curJ);

    // ---- PASS 1: forward tile acc = A·B^T
    {
      f32x16 acc[2][2] = {};
      #pragma unroll
      for (int ks = 0; ks < 4; ks++) {
        const int u = ((2 * ks + half) ^ e7) * 32;
        i32x8 af[2], bf[2];
        af[0] = *(const i32x8*)(As + rowA0 + u);
        af[1] = *(const i32x8*)(As + rowA0 + 32 * 256 + u);
        bf[0] = *(const i32x8*)(Bs + rowB0 + u);
        bf[1] = *(const i32x8*)(Bs + rowB0 + 32 * 256 + u);
        #pragma unroll
        for (int mi = 0; mi < 2; mi++)
          #pragma unroll
          for (int ni = 0; ni < 2; ni++)
            acc[mi][ni] = __builtin_amdgcn_mfma_scale_f32_32x32x64_f8f6f4(
                af[mi], bf[ni], acc[mi][ni], 0, 0, 0, 0x7F7F7F7F, 0, 0x7F7F7F7F);
      }
      const int colBaseF = curJ * 128 + wc * 64;
      #pragma unroll
      for (int ni = 0; ni < 2; ni++) {
        float cs = 0.0f;
        #pragma unroll
        for (int mi = 0; mi < 2; mi++)
          #pragma unroll
          for (int r = 0; r < 16; r++)
            if (((l31 ^ r) & 3) != 0)          // include iff col%4 != row%4
              cs += __builtin_amdgcn_exp2f(acc[mi][ni][r]);
        cs += __shfl_xor(cs, 32, 64);
        if (half == 0) atomicAdd(&den[colBaseF + ni * 32 + l31], cs);
      }
    }

    // ---- PASS 2 (off-diagonal): mirror tile accT = B·A^T, same LDS frags
    if (offd) {
      f32x16 accT[2][2] = {};
      #pragma unroll
      for (int ks = 0; ks < 4; ks++) {
        const int u = ((2 * ks + half) ^ e7) * 32;
        i32x8 af[2], bf[2];
        af[0] = *(const i32x8*)(As + rowA0 + u);
        af[1] = *(const i32x8*)(As + rowA0 + 32 * 256 + u);
        bf[0] = *(const i32x8*)(Bs + rowB0 + u);
        bf[1] = *(const i32x8*)(Bs + rowB0 + 32 * 256 + u);
        #pragma unroll
        for (int ni = 0; ni < 2; ni++)
          #pragma unroll
          for (int mi = 0; mi < 2; mi++)
            accT[ni][mi] = __builtin_amdgcn_mfma_scale_f32_32x32x64_f8f6f4(
                bf[ni], af[mi], accT[ni][mi], 0, 0, 0, 0x7F7F7F7F, 0, 0x7F7F7F7F);
      }
      // all LDS reads done; raw barrier (prefetch loads stay in flight)
      BARRIER_NO_VMDRAIN();
      const int colBaseT = curI * 128 + wr * 64;
      #pragma unroll
      for (int mi = 0; mi < 2; mi++) {
        float cs = 0.0f;
        #pragma unroll
        for (int ni = 0; ni < 2; ni++)
          #pragma unroll
          for (int r = 0; r < 16; r++)
            if (((l31 ^ r) & 3) != 0)
              cs += __builtin_amdgcn_exp2f(accT[ni][mi][r]);
        cs += __shfl_xor(cs, 32, 64);
        if (half == 0) atomicAdd(&den[colBaseT + mi * 32 + l31], cs);
      }
    } else {
      BARRIER_NO_VMDRAIN();                  // uniform: all blocks barrier once
    }

    if (!more) break;
    curI = nI; curJ = nJ; tcur = tnext;
  }
}

// ---------------------------------------------------------------------------
// Kernel 3: numerators (fp32, exact path) + final loss.
// ---------------------------------------------------------------------------
__global__ __launch_bounds__(256) void loss_kernel(const float* __restrict__ x,
                                                   const float* __restrict__ invn,
                                                   const float* __restrict__ den,
                                                   float* __restrict__ out) {
  __shared__ float part[4];
  const int wave = threadIdx.x >> 6, lane = threadIdx.x & 63;
  const int p = blockIdx.x * 4 + wave;
  const float4 a = ((const float4*)(x + (size_t)p * DIM))[lane];
  const float4 b = ((const float4*)(x + (size_t)(BATCH_ + p) * DIM))[lane];
  const float4 c = ((const float4*)(x + (size_t)(2*BATCH_ + p) * DIM))[lane];
  float d12 = a.x*b.x + a.y*b.y + a.z*b.z + a.w*b.w;
  float d13 = a.x*c.x + a.y*c.y + a.z*c.z + a.w*c.w;
  float d23 = b.x*c.x + b.y*c.y + b.z*c.z + b.w*c.w;
  #pragma unroll
  for (int off = 1; off < 64; off <<= 1) {
    d12 += __shfl_xor(d12, off, 64);
    d13 += __shfl_xor(d13, off, 64);
    d23 += __shfl_xor(d23, off, 64);
  }
  if (lane == 0) {
    const float s1 = invn[p], s2 = invn[BATCH_ + p], s3 = invn[2*BATCH_ + p];
    const float z12 = d12 * s1 * s2 * 10.0f;
    const float z13 = d13 * s1 * s3 * 10.0f;
    const float z23 = d23 * s2 * s3 * 10.0f;
    const float n12 = __expf(z12), n13 = __expf(z13), n23 = __expf(z23);
    const float e1 = den[p], e2 = den[BATCH_ + p], e3 = den[2*BATCH_ + p];
    part[wave] = __logf(n12 + e1) + __logf(n12 + e2) - 2.0f * z12
               + __logf(n13 + e1) + __logf(n13 + e3) - 2.0f * z13
               + __logf(n23 + e2) + __logf(n23 + e3) - 2.0f * z23;
  }
  __syncthreads();
  if (threadIdx.x == 0) {
    atomicAdd(out, (part[0] + part[1] + part[2] + part[3]) * (1.0f / (2.0f * BATCH_)));
  }
}

// ---------------------------------------------------------------------------
extern "C" void kernel_launch(void* const* d_in, const int* in_sizes, int n_in,
                              void* d_out, int out_size, void* d_ws, size_t ws_size,
                              hipStream_t stream) {
  const float* x = (const float*)d_in[0];
  float* out = (float*)d_out;

  char* ws = (char*)d_ws;
  uint8_t* xn   = (uint8_t*)ws;                                      // 3 MB fp8
  float*   invn = (float*)(ws + (size_t)BS_TOT * DIM);               // 48 KB
  float*   den  = (float*)(ws + (size_t)BS_TOT * DIM + BS_TOT * 4);  // 48 KB

  normalize_kernel<<<BS_TOT / 4, 256, 0, stream>>>(x, xn, invn, den, out, out_size);
  gemm_den_kernel<<<NBLOCKS, 256, 0, stream>>>(xn, den);
  loss_kernel<<<BATCH_ / 4, 256, 0, stream>>>(x, invn, den, out);
}

// Round 17
// 121.551 us; speedup vs baseline: 1.5940x; 1.5940x over previous
//
#include <hip/hip_runtime.h>
#include <hip/hip_bf16.h>
#include <cstdint>
#include <cstddef>

// Problem constants
#define BS_TOT  12288   // 3 * 4096 rows
#define DIM     256     // embedding dim
#define BATCH_  4096
#define NTILE   96      // BS_TOT / 128
#define NPAIR   4656    // NTILE*(NTILE+1)/2 — triangular tile pairs (incl diag)
#define NBLOCKS 512     // persistent, 2 blocks/CU; ~9 contiguous pairs each

typedef float f32x16 __attribute__((ext_vector_type(16)));
typedef int   i32x8  __attribute__((ext_vector_type(8)));

// ---------------------------------------------------------------------------
// Kernel 1: row-normalize -> fp8 e4m3 rows scaled by sqrt(10*log2(e)):
// acc = 10*log2(e)*cos, so epilogue exp(10 cos) = exp2(acc) = bare v_exp_f32.
// Also fp32 inv-norms (exact numerator path) + zero den + zero out.
// ---------------------------------------------------------------------------
__global__ __launch_bounds__(256) void normalize_kernel(const float* __restrict__ x,
                                                        uint8_t* __restrict__ xn,
                                                        float* __restrict__ invn,
                                                        float* __restrict__ den,
                                                        float* __restrict__ out,
                                                        int osz) {
  if (blockIdx.x == 0 && (int)threadIdx.x < osz) out[threadIdx.x] = 0.0f;
  const int wave = threadIdx.x >> 6;
  const int lane = threadIdx.x & 63;
  const int row  = blockIdx.x * 4 + wave;
  const float4 v = ((const float4*)(x + (size_t)row * DIM))[lane];
  float ss = v.x*v.x + v.y*v.y + v.z*v.z + v.w*v.w;
  #pragma unroll
  for (int off = 1; off < 64; off <<= 1) ss += __shfl_xor(ss, off, 64);
  const float s = 1.0f / fmaxf(sqrtf(ss), 1e-6f);
  if (lane == 0) { invn[row] = s; den[row] = 0.0f; }
  const float sc = s * 3.79828286f;   // sqrt(10 * log2(e))
  unsigned int w = __builtin_amdgcn_cvt_pk_fp8_f32(v.x * sc, v.y * sc, 0u, false);
  w = __builtin_amdgcn_cvt_pk_fp8_f32(v.z * sc, v.w * sc, w, true);
  ((unsigned int*)(xn + (size_t)row * DIM))[lane] = w;
}

// ---------------------------------------------------------------------------
// ROW-MAJOR triangular decode: t -> (tI, tJ>=tI).
// Row i starts at S(i) = i*(193-i)/2 (96, 95, ... pairs per row).
// ---------------------------------------------------------------------------
__device__ __forceinline__ void decode_rowmajor(int t, int& tI, int& tJ) {
  int i = (int)((193.0f - sqrtf(193.0f * 193.0f - 8.0f * (float)t)) * 0.5f);
  if (i < 0) i = 0;
  while ((i + 1) * (193 - (i + 1)) / 2 <= t) i++;   // S(i+1) <= t -> advance
  while (i * (193 - i) / 2 > t) i--;                // S(i)  > t  -> back up
  tI = i;
  tJ = i + (t - i * (193 - i) / 2);
}

// Raw workgroup barrier: lgkmcnt-only (covers ds_write/ds_read completion),
// does NOT drain vmcnt — so epilogue atomics and nothing else get waited on.
#define BARRIER_LGKM() asm volatile("s_waitcnt lgkmcnt(0)\n\ts_barrier" ::: "memory")

// ---------------------------------------------------------------------------
// Kernel 2: PERSISTENT symmetric triangular GEMM, MX-scaled fp8 32x32x64,
// R12 shape (256 thr, 4 waves 2x2, 2 blocks/CU, mirror MFMA in one pass —
// best measured structure: 52.5 us), with A-PANEL REUSE:
// each block owns ~9 CONSECUTIVE row-major pairs (tI fixed, tJ ascending),
// so the A panel is staged once per row-change only and stays resident in
// LDS; per pair only B (32 KB) is loaded+staged. Halves the per-pair
// serial load->ds_write->drain chain and the HBM/L2 fetch volume.
// R13 proved persistence is cost-free; R14/R16 proved cross-barrier
// register prefetch spills — this keeps all staging registers transient
// within an iteration (R12-proven: VGPR 88, no spill).
//
//   acc  = A·B^T -> masked col sums -> den[tJ cols]
//   accT = B·A^T -> masked col sums -> den[tI cols]   (off-diagonal only)
//
// LDS: 32-B-unit XOR swizzle  addr = row*256 + ((k32 ^ (row&7))*32) + sub16
// Fragment ks: lane (l31,half) reads 32 B at unit (2ks+half)^(l31&7),
// one aligned i32x8 (2 x ds_read_b128).
// C/D layout (HW-verified): col = lane&31, row = (reg&3)+8*(reg>>2)+4*half.
// Mask: exclude iff col%4 == row%4  ->  ((l31 ^ r) & 3) == 0.
// ---------------------------------------------------------------------------
__global__ __launch_bounds__(256, 2) void gemm_den_kernel(const uint8_t* __restrict__ xn,
                                                          float* __restrict__ den) {
  __shared__ __align__(16) uint8_t As[128 * 256];   // 32 KB (resident per row)
  __shared__ __align__(16) uint8_t Bs[128 * 256];   // 32 KB (per pair)

  const int tid  = threadIdx.x;
  const int wave = tid >> 6, lane = tid & 63;
  const int wr   = wave >> 1, wc = wave & 1;
  const int l31  = lane & 31, half = lane >> 5;
  const int e7   = l31 & 7;
  const int rowA0 = (wr * 64 + l31) * 256;
  const int rowB0 = (wc * 64 + l31) * 256;

  // per-thread staging maps (constant across pairs)
  size_t goff[8]; int wadr[8];
  #pragma unroll
  for (int c = 0; c < 8; c++) {
    const int q   = c * 256 + tid;
    const int row = q >> 4, k16 = q & 15;
    goff[c] = (size_t)row * DIM + (size_t)k16 * 16;
    wadr[c] = row * 256 + (((k16 >> 1) ^ (row & 7)) * 32) + (k16 & 1) * 16;
  }

  // contiguous chunk of row-major pairs
  const int b     = blockIdx.x;
  const int start = (int)((long)b * NPAIR / NBLOCKS);
  const int end   = (int)((long)(b + 1) * NPAIR / NBLOCKS);

  int prevI = -1;
  for (int t = start; t < end; t++) {
    int tI, tJ;
    decode_rowmajor(t, tI, tJ);
    const bool offd = (tI != tJ);
    const bool newA = (tI != prevI);
    prevI = tI;

    // ---- stage B (always) + A (on row change); registers are transient.
    {
      const uint8_t* Bb = xn + (size_t)tJ * 128 * DIM;
      int4 chB[8];
      #pragma unroll
      for (int c = 0; c < 8; c++) chB[c] = *(const int4*)(Bb + goff[c]);
      if (newA) {
        const uint8_t* Ab = xn + (size_t)tI * 128 * DIM;
        int4 chA[8];
        #pragma unroll
        for (int c = 0; c < 8; c++) chA[c] = *(const int4*)(Ab + goff[c]);
        #pragma unroll
        for (int c = 0; c < 8; c++) *(int4*)(As + wadr[c]) = chA[c];
      }
      #pragma unroll
      for (int c = 0; c < 8; c++) *(int4*)(Bs + wadr[c]) = chB[c];
    }
    BARRIER_LGKM();   // ds_writes visible to all waves (vm deps already waited)

    // ---- K-loop: 4 steps of K=64; 4 frag loads + 4 fwd MFMA (+4 mirror).
    f32x16 acc[2][2]  = {};
    f32x16 accT[2][2] = {};
    #pragma unroll
    for (int ks = 0; ks < 4; ks++) {
      const int u = ((2 * ks + half) ^ e7) * 32;
      i32x8 af[2], bf[2];
      af[0] = *(const i32x8*)(As + rowA0 + u);
      af[1] = *(const i32x8*)(As + rowA0 + 32 * 256 + u);
      bf[0] = *(const i32x8*)(Bs + rowB0 + u);
      bf[1] = *(const i32x8*)(Bs + rowB0 + 32 * 256 + u);
      #pragma unroll
      for (int mi = 0; mi < 2; mi++)
        #pragma unroll
        for (int ni = 0; ni < 2; ni++)
          acc[mi][ni] = __builtin_amdgcn_mfma_scale_f32_32x32x64_f8f6f4(
              af[mi], bf[ni], acc[mi][ni], 0, 0, 0, 0x7F7F7F7F, 0, 0x7F7F7F7F);
      if (offd) {
        #pragma unroll
        for (int ni = 0; ni < 2; ni++)
          #pragma unroll
          for (int mi = 0; mi < 2; mi++)
            accT[ni][mi] = __builtin_amdgcn_mfma_scale_f32_32x32x64_f8f6f4(
                bf[ni], af[mi], accT[ni][mi], 0, 0, 0, 0x7F7F7F7F, 0, 0x7F7F7F7F);
      }
    }
    BARRIER_LGKM();   // all LDS reads done before next iteration's ds_writes

    // ---- epilogue: E = exp2(acc) (temp+log2e pre-folded); masked col sums.
    {
      const int colBaseF = tJ * 128 + wc * 64;
      #pragma unroll
      for (int ni = 0; ni < 2; ni++) {
        float cs = 0.0f;
        #pragma unroll
        for (int mi = 0; mi < 2; mi++)
          #pragma unroll
          for (int r = 0; r < 16; r++)
            if (((l31 ^ r) & 3) != 0)          // include iff col%4 != row%4
              cs += __builtin_amdgcn_exp2f(acc[mi][ni][r]);
        cs += __shfl_xor(cs, 32, 64);
        if (half == 0) atomicAdd(&den[colBaseF + ni * 32 + l31], cs);
      }
      if (offd) {                              // mirror tile: cols = tI rows
        const int colBaseT = tI * 128 + wr * 64;
        #pragma unroll
        for (int mi = 0; mi < 2; mi++) {
          float cs = 0.0f;
          #pragma unroll
          for (int ni = 0; ni < 2; ni++)
            #pragma unroll
            for (int r = 0; r < 16; r++)
              if (((l31 ^ r) & 3) != 0)
                cs += __builtin_amdgcn_exp2f(accT[ni][mi][r]);
          cs += __shfl_xor(cs, 32, 64);
          if (half == 0) atomicAdd(&den[colBaseT + mi * 32 + l31], cs);
        }
      }
    }
  }
}

// ---------------------------------------------------------------------------
// Kernel 3: numerators (fp32, exact path) + final loss.
// ---------------------------------------------------------------------------
__global__ __launch_bounds__(256) void loss_kernel(const float* __restrict__ x,
                                                   const float* __restrict__ invn,
                                                   const float* __restrict__ den,
                                                   float* __restrict__ out) {
  __shared__ float part[4];
  const int wave = threadIdx.x >> 6, lane = threadIdx.x & 63;
  const int p = blockIdx.x * 4 + wave;
  const float4 a = ((const float4*)(x + (size_t)p * DIM))[lane];
  const float4 b = ((const float4*)(x + (size_t)(BATCH_ + p) * DIM))[lane];
  const float4 c = ((const float4*)(x + (size_t)(2*BATCH_ + p) * DIM))[lane];
  float d12 = a.x*b.x + a.y*b.y + a.z*b.z + a.w*b.w;
  float d13 = a.x*c.x + a.y*c.y + a.z*c.z + a.w*c.w;
  float d23 = b.x*c.x + b.y*c.y + b.z*c.z + b.w*c.w;
  #pragma unroll
  for (int off = 1; off < 64; off <<= 1) {
    d12 += __shfl_xor(d12, off, 64);
    d13 += __shfl_xor(d13, off, 64);
    d23 += __shfl_xor(d23, off, 64);
  }
  if (lane == 0) {
    const float s1 = invn[p], s2 = invn[BATCH_ + p], s3 = invn[2*BATCH_ + p];
    const float z12 = d12 * s1 * s2 * 10.0f;
    const float z13 = d13 * s1 * s3 * 10.0f;
    const float z23 = d23 * s2 * s3 * 10.0f;
    const float n12 = __expf(z12), n13 = __expf(z13), n23 = __expf(z23);
    const float e1 = den[p], e2 = den[BATCH_ + p], e3 = den[2*BATCH_ + p];
    part[wave] = __logf(n12 + e1) + __logf(n12 + e2) - 2.0f * z12
               + __logf(n13 + e1) + __logf(n13 + e3) - 2.0f * z13
               + __logf(n23 + e2) + __logf(n23 + e3) - 2.0f * z23;
  }
  __syncthreads();
  if (threadIdx.x == 0) {
    atomicAdd(out, (part[0] + part[1] + part[2] + part[3]) * (1.0f / (2.0f * BATCH_)));
  }
}

// ---------------------------------------------------------------------------
extern "C" void kernel_launch(void* const* d_in, const int* in_sizes, int n_in,
                              void* d_out, int out_size, void* d_ws, size_t ws_size,
                              hipStream_t stream) {
  const float* x = (const float*)d_in[0];
  float* out = (float*)d_out;

  char* ws = (char*)d_ws;
  uint8_t* xn   = (uint8_t*)ws;                                      // 3 MB fp8
  float*   invn = (float*)(ws + (size_t)BS_TOT * DIM);               // 48 KB
  float*   den  = (float*)(ws + (size_t)BS_TOT * DIM + BS_TOT * 4);  // 48 KB

  normalize_kernel<<<BS_TOT / 4, 256, 0, stream>>>(x, xn, invn, den, out, out_size);
  gemm_den_kernel<<<NBLOCKS, 256, 0, stream>>>(xn, den);
  loss_kernel<<<BATCH_ / 4, 256, 0, stream>>>(x, invn, den, out);
}